// Round 1
// baseline (513.978 us; speedup 1.0000x reference)
//
#include <hip/hip_runtime.h>

typedef float f32x4 __attribute__((ext_vector_type(4)));
typedef short bf16x8 __attribute__((ext_vector_type(8)));
typedef unsigned short u16;

#define B_DIM 16384
#define IN_DIM 768
#define H_DIM 1024
#define R_DIM 64

__device__ __forceinline__ u16 f2b(float f) {
    unsigned int u = __builtin_bit_cast(unsigned int, f);
    u += 0x7FFFu + ((u >> 16) & 1u);
    return (u16)(u >> 16);
}
__device__ __forceinline__ float sigm(float z) { return 1.f / (1.f + __expf(-z)); }
__device__ __forceinline__ float tanh_(float z) { return 2.f / (1.f + __expf(-2.f * z)) - 1.f; }

// ---------------- prep: weight transposes (bf16) + diag coefficient vectors ----------------
__global__ __launch_bounds__(256) void prep_kernel(
    const float* Wu0, const float* Wu1, const float* Wu2, const float* Wu3,
    const float* Uu0, const float* Uu1, const float* Uu2, const float* Uu3,
    const float* W0, const float* W1, const float* W2, const float* W3,
    const float* U0, const float* U1, const float* U2, const float* U3,
    const float* W_dia, const float* U_dia,
    u16* WuT, u16* UuT, u16* CatT, float* dw, float* du)
{
    const float* Wu[4] = {Wu0, Wu1, Wu2, Wu3};
    const float* Uu[4] = {Uu0, Uu1, Uu2, Uu3};
    const float* W[4]  = {W0, W1, W2, W3};
    const float* U[4]  = {U0, U1, U2, U3};
    int idx = blockIdx.x * 256 + threadIdx.x;
    int stride = gridDim.x * 256;
#pragma unroll
    for (int g = 0; g < 4; ++g) {
        // WuT[g*64+n][k] = Wu_g[k][n]   (n<64, k<768)
        for (int t = idx; t < 64 * IN_DIM; t += stride) {
            int n = t / IN_DIM, k = t - n * IN_DIM;
            WuT[(size_t)(g * 64 + n) * IN_DIM + k] = f2b(Wu[g][k * 64 + n]);
        }
        // UuT[g*64+n][k] = Uu_g[k][n]   (k<1024)
        for (int t = idx; t < 64 * H_DIM; t += stride) {
            int n = t >> 10, k = t & 1023;
            UuT[(size_t)(g * 64 + n) * H_DIM + k] = f2b(Uu[g][k * 64 + n]);
        }
        // CatT[g][j][k]: k<64 -> W_g[k][j], else U_g[k-64][j]
        for (int t = idx; t < H_DIM * 128; t += stride) {
            int n = t >> 7, k = t & 127;
            float v = (k < 64) ? W[g][k * H_DIM + n] : U[g][(k - 64) * H_DIM + n];
            CatT[(size_t)g * (H_DIM * 128) + t] = f2b(v);
        }
        // dw[g][j] = W_dia[j] - sum_r Wu_g[j][r]*W_g[r][j]
        for (int j = idx; j < IN_DIM; j += stride) {
            float s = 0.f;
            for (int r = 0; r < 64; ++r) s += Wu[g][j * 64 + r] * W[g][r * H_DIM + j];
            dw[g * IN_DIM + j] = W_dia[j] - s;
        }
        // du[g][j] = U_dia[j] - sum_r Uu_g[j][r]*U_g[r][j]
        for (int j = idx; j < H_DIM; j += stride) {
            float s = 0.f;
            for (int r = 0; r < 64; ++r) s += Uu[g][j * 64 + r] * U[g][r * H_DIM + j];
            du[g * H_DIM + j] = U_dia[j] - s;
        }
    }
}

// ---------------- GEMM A: M[b, g*128 + part*64 + r] = (part? h@Uu : x@Wu) ----------------
__global__ __launch_bounds__(256) void gemmA_kernel(
    const float* __restrict__ x, const float* __restrict__ h,
    const u16* __restrict__ WuT, const u16* __restrict__ UuT,
    u16* __restrict__ M)
{
    __shared__ u16 lsA[64 * 64];
    __shared__ u16 lsB[64 * 64];
    const int tid = threadIdx.x;
    const int lane = tid & 63;
    const int wid = tid >> 6;
    const int wm = wid >> 1, wn = wid & 1;
    const int cb = blockIdx.x, rb = blockIdx.y, part = blockIdx.z;
    const float* A = part ? h : x;
    const u16* BT = part ? UuT : WuT;
    const int K = part ? H_DIM : IN_DIM;

    const float* Ab = A + (size_t)rb * 64 * K;
    const u16* Bb = BT + (size_t)cb * 64 * K;

    f32x4 acc[2][2] = {};
    for (int k0 = 0; k0 < K; k0 += 64) {
        __syncthreads();
        // stage A tile (fp32 -> bf16), 64x64
#pragma unroll
        for (int qq = 0; qq < 4; ++qq) {
            int q = tid + qq * 256;
            int row = q >> 4, kq = (q & 15) << 2;
            float4 v = *reinterpret_cast<const float4*>(Ab + (size_t)row * K + k0 + kq);
            ushort4 b;
            b.x = f2b(v.x); b.y = f2b(v.y); b.z = f2b(v.z); b.w = f2b(v.w);
            int byte = (row << 7) + (kq << 1);
            byte ^= (row & 7) << 4;
            *reinterpret_cast<ushort4*>(reinterpret_cast<char*>(lsA) + byte) = b;
        }
        // stage B tile [64 n][64 k] bf16
#pragma unroll
        for (int uu = 0; uu < 2; ++uu) {
            int u = tid + uu * 256;
            int n = u >> 3, k8 = (u & 7) << 3;
            uint4 v = *reinterpret_cast<const uint4*>(Bb + (size_t)n * K + k0 + k8);
            int byte = (n << 7) + (k8 << 1);
            byte ^= (n & 7) << 4;
            *reinterpret_cast<uint4*>(reinterpret_cast<char*>(lsB) + byte) = v;
        }
        __syncthreads();
#pragma unroll
        for (int ks = 0; ks < 2; ++ks) {
            const int kb = ks * 64 + ((lane >> 4) << 4);
            bf16x8 af[2], bf[2];
#pragma unroll
            for (int fm = 0; fm < 2; ++fm) {
                int row = wm * 32 + fm * 16 + (lane & 15);
                af[fm] = *reinterpret_cast<const bf16x8*>(
                    reinterpret_cast<const char*>(lsA) + (((row << 7) + kb) ^ ((row & 7) << 4)));
            }
#pragma unroll
            for (int fn = 0; fn < 2; ++fn) {
                int n = wn * 32 + fn * 16 + (lane & 15);
                bf[fn] = *reinterpret_cast<const bf16x8*>(
                    reinterpret_cast<const char*>(lsB) + (((n << 7) + kb) ^ ((n & 7) << 4)));
            }
#pragma unroll
            for (int fm = 0; fm < 2; ++fm)
#pragma unroll
                for (int fn = 0; fn < 2; ++fn)
                    acc[fm][fn] = __builtin_amdgcn_mfma_f32_16x16x32_bf16(af[fm], bf[fn], acc[fm][fn], 0, 0, 0);
        }
    }
    // epilogue: scatter to gate-blocked M columns
#pragma unroll
    for (int fm = 0; fm < 2; ++fm)
#pragma unroll
        for (int fn = 0; fn < 2; ++fn)
#pragma unroll
            for (int i = 0; i < 4; ++i) {
                int row = rb * 64 + wm * 32 + fm * 16 + ((lane >> 4) << 2) + i;
                int n = cb * 64 + wn * 32 + fn * 16 + (lane & 15);
                int g = n >> 6, r = n & 63;
                int mcol = g * 128 + part * 64 + r;
                M[(size_t)row * 512 + mcol] = f2b(acc[fm][fn][i]);
            }
}

// ---------------- GEMM B + fused LSTM epilogue ----------------
__global__ __launch_bounds__(256) void gate_kernel(
    const u16* __restrict__ M, const u16* __restrict__ CatT,
    const float* __restrict__ dw, const float* __restrict__ du,
    const float* __restrict__ bias_f, const float* __restrict__ bias_i,
    const float* __restrict__ bias_c, const float* __restrict__ bias_o,
    const float* __restrict__ x, const float* __restrict__ h,
    const float* __restrict__ c, float* __restrict__ out)
{
    __shared__ u16 lsM[64 * 128];
    __shared__ u16 lsC[64 * 128];
    const int tid = threadIdx.x, lane = tid & 63, wid = tid >> 6;
    const int wm = wid >> 1, wn = wid & 1;
    const int cb = blockIdx.x, rb = blockIdx.y;

    f32x4 acc[4][2][2] = {};
#pragma unroll
    for (int g = 0; g < 4; ++g) {
        __syncthreads();
        // stage M tile [64 rows][128 k]
#pragma unroll
        for (int uu = 0; uu < 4; ++uu) {
            int u = tid + uu * 256;
            int row = u >> 4, kc = (u & 15) << 3;
            uint4 v = *reinterpret_cast<const uint4*>(M + ((size_t)(rb * 64 + row)) * 512 + g * 128 + kc);
            int byte = (row << 8) + (kc << 1);
            byte ^= (row & 7) << 4;
            *reinterpret_cast<uint4*>(reinterpret_cast<char*>(lsM) + byte) = v;
        }
        // stage Cat tile [64 n][128 k]
        const u16* Cg = CatT + ((size_t)g * H_DIM + cb * 64) * 128;
#pragma unroll
        for (int uu = 0; uu < 4; ++uu) {
            int u = tid + uu * 256;
            int n = u >> 4, kc = (u & 15) << 3;
            uint4 v = *reinterpret_cast<const uint4*>(Cg + (size_t)n * 128 + kc);
            int byte = (n << 8) + (kc << 1);
            byte ^= (n & 7) << 4;
            *reinterpret_cast<uint4*>(reinterpret_cast<char*>(lsC) + byte) = v;
        }
        __syncthreads();
#pragma unroll
        for (int ks = 0; ks < 4; ++ks) {
            const int kb = ks * 64 + ((lane >> 4) << 4);
            bf16x8 af[2], bfr[2];
#pragma unroll
            for (int fm = 0; fm < 2; ++fm) {
                int row = wm * 32 + fm * 16 + (lane & 15);
                af[fm] = *reinterpret_cast<const bf16x8*>(
                    reinterpret_cast<const char*>(lsM) + (((row << 8) + kb) ^ ((row & 7) << 4)));
            }
#pragma unroll
            for (int fn = 0; fn < 2; ++fn) {
                int n = wn * 32 + fn * 16 + (lane & 15);
                bfr[fn] = *reinterpret_cast<const bf16x8*>(
                    reinterpret_cast<const char*>(lsC) + (((n << 8) + kb) ^ ((n & 7) << 4)));
            }
#pragma unroll
            for (int fm = 0; fm < 2; ++fm)
#pragma unroll
                for (int fn = 0; fn < 2; ++fn)
                    acc[g][fm][fn] = __builtin_amdgcn_mfma_f32_16x16x32_bf16(af[fm], bfr[fn], acc[g][fm][fn], 0, 0, 0);
        }
    }
    // fused LSTM epilogue
    const bool hasx = (cb < 12);  // cols [cb*64, cb*64+64) < 768
#pragma unroll
    for (int fn = 0; fn < 2; ++fn) {
        int col = cb * 64 + wn * 32 + fn * 16 + (lane & 15);
        float b0 = bias_f[col], b1 = bias_i[col], b2 = bias_c[col], b3 = bias_o[col];
        float du0 = du[col], du1 = du[H_DIM + col], du2 = du[2 * H_DIM + col], du3 = du[3 * H_DIM + col];
        float dw0 = 0.f, dw1 = 0.f, dw2 = 0.f, dw3 = 0.f;
        if (hasx) {
            dw0 = dw[col]; dw1 = dw[IN_DIM + col];
            dw2 = dw[2 * IN_DIM + col]; dw3 = dw[3 * IN_DIM + col];
        }
#pragma unroll
        for (int fm = 0; fm < 2; ++fm)
#pragma unroll
            for (int i = 0; i < 4; ++i) {
                int row = rb * 64 + wm * 32 + fm * 16 + ((lane >> 4) << 2) + i;
                size_t idx = (size_t)row * H_DIM + col;
                float hv = h[idx], cv = c[idx];
                float xv = hasx ? x[(size_t)row * IN_DIM + col] : 0.f;
                float p0 = acc[0][fm][fn][i] + b0 + hv * du0 + xv * dw0;
                float p1 = acc[1][fm][fn][i] + b1 + hv * du1 + xv * dw1;
                float p2 = acc[2][fm][fn][i] + b2 + hv * du2 + xv * dw2;
                float p3 = acc[3][fm][fn][i] + b3 + hv * du3 + xv * dw3;
                float fg = sigm(p0), ig = sigm(p1), gg = tanh_(p2), og = sigm(p3);
                float cn = fg * cv + ig * gg;
                float hn = og * tanh_(cn);
                out[idx] = hn;
                out[(size_t)B_DIM * H_DIM + idx] = cn;
            }
    }
}

extern "C" void kernel_launch(void* const* d_in, const int* in_sizes, int n_in,
                              void* d_out, int out_size, void* d_ws, size_t ws_size,
                              hipStream_t stream)
{
    const float* x = (const float*)d_in[0];
    const float* h = (const float*)d_in[1];
    const float* c = (const float*)d_in[2];

    char* ws = (char*)d_ws;
    u16* M    = (u16*)(ws);                  // 16384*512*2      = 16,777,216 B
    u16* WuT  = (u16*)(ws + 16777216);       // 256*768*2        =    393,216 B
    u16* UuT  = (u16*)(ws + 17170432);       // 256*1024*2       =    524,288 B
    u16* CatT = (u16*)(ws + 17694720);       // 4*1024*128*2     =  1,048,576 B
    float* dw = (float*)(ws + 18743296);     // 4*768*4          =     12,288 B
    float* du = (float*)(ws + 18755584);     // 4*1024*4         =     16,384 B

    prep_kernel<<<dim3(64), dim3(256), 0, stream>>>(
        (const float*)d_in[3], (const float*)d_in[4], (const float*)d_in[5], (const float*)d_in[6],
        (const float*)d_in[7], (const float*)d_in[8], (const float*)d_in[9], (const float*)d_in[10],
        (const float*)d_in[11], (const float*)d_in[12], (const float*)d_in[13], (const float*)d_in[14],
        (const float*)d_in[15], (const float*)d_in[16], (const float*)d_in[17], (const float*)d_in[18],
        (const float*)d_in[23], (const float*)d_in[24],
        WuT, UuT, CatT, dw, du);

    gemmA_kernel<<<dim3(4, 256, 2), dim3(256), 0, stream>>>(x, h, WuT, UuT, M);

    gate_kernel<<<dim3(16, 256), dim3(256), 0, stream>>>(
        M, CatT, dw, du,
        (const float*)d_in[19], (const float*)d_in[20], (const float*)d_in[21], (const float*)d_in[22],
        x, h, c, (float*)d_out);
}